// Round 1
// baseline (111.344 us; speedup 1.0000x reference)
//
#include <hip/hip_runtime.h>

#define NB 65536
#define NUM_T 200

__global__ __launch_bounds__(256, 1) void sir_rk4_kernel(
    const float4* __restrict__ params, float* __restrict__ out)
{
    const int b = blockIdx.x * 256 + threadIdx.x;

    const float4 p = params[b];
    const float beta  = p.x;
    const float gamma = p.y;
    float S = p.z;
    float I = p.w;

    const float step = 100.0f / 199.0f;   // linspace step in fp32
    float* o = out + (size_t)b * (NUM_T * 3);
    float tprev = 0.0f;

    for (int g = 0; g < NUM_T / 4; ++g) {
        float buf[12];
        #pragma unroll
        for (int j = 0; j < 4; ++j) {
            const int i = g * 4 + j;
            if (i > 0) {
                // dt exactly as ts[i] - ts[i-1] with ts = i*step (fp32)
                const float tcur = step * (float)i;
                const float dt   = tcur - tprev;
                tprev = tcur;
                const float h  = dt * 0.125f;       // dt / SUBSTEPS (exact)
                const float h2 = 0.5f * h;
                const float h6 = h * (1.0f / 6.0f);
                #pragma unroll
                for (int s = 0; s < 8; ++s) {
                    // k1
                    float bSI = beta * S * I;
                    float gI  = gamma * I;
                    const float k1S = -bSI;
                    const float k1I = bSI - gI;
                    const float S2 = fmaf(h2, k1S, S);
                    const float I2 = fmaf(h2, k1I, I);
                    // k2
                    bSI = beta * S2 * I2;
                    gI  = gamma * I2;
                    const float k2S = -bSI;
                    const float k2I = bSI - gI;
                    const float S3 = fmaf(h2, k2S, S);
                    const float I3 = fmaf(h2, k2I, I);
                    // k3
                    bSI = beta * S3 * I3;
                    gI  = gamma * I3;
                    const float k3S = -bSI;
                    const float k3I = bSI - gI;
                    const float S4 = fmaf(h, k3S, S);
                    const float I4 = fmaf(h, k3I, I);
                    // k4
                    bSI = beta * S4 * I4;
                    gI  = gamma * I4;
                    const float k4S = -bSI;
                    const float k4I = bSI - gI;
                    // combine
                    float aS = fmaf(2.0f, k2S, k1S);
                    aS = fmaf(2.0f, k3S, aS);
                    aS += k4S;
                    float aI = fmaf(2.0f, k2I, k1I);
                    aI = fmaf(2.0f, k3I, aI);
                    aI += k4I;
                    S = fmaf(h6, aS, S);
                    I = fmaf(h6, aI, I);
                }
            }
            buf[j * 3 + 0] = S;
            buf[j * 3 + 1] = I;
            buf[j * 3 + 2] = 1.0f - S - I;   // R conserved: S+I+R == 1
        }
        float4* o4 = reinterpret_cast<float4*>(o + g * 12);
        o4[0] = make_float4(buf[0], buf[1], buf[2],  buf[3]);
        o4[1] = make_float4(buf[4], buf[5], buf[6],  buf[7]);
        o4[2] = make_float4(buf[8], buf[9], buf[10], buf[11]);
    }
}

extern "C" void kernel_launch(void* const* d_in, const int* in_sizes, int n_in,
                              void* d_out, int out_size, void* d_ws, size_t ws_size,
                              hipStream_t stream) {
    (void)in_sizes; (void)n_in; (void)out_size; (void)d_ws; (void)ws_size;
    const float4* params = (const float4*)d_in[0];
    float* out = (float*)d_out;
    sir_rk4_kernel<<<NB / 256, 256, 0, stream>>>(params, out);
}

// Round 2
// 76.266 us; speedup vs baseline: 1.4599x; 1.4599x over previous
//
#include <hip/hip_runtime.h>

#define NB 65536
#define NUM_T 200

__global__ __launch_bounds__(256, 1) void sir_rk4_kernel(
    const float4* __restrict__ params, float* __restrict__ out)
{
    const int b = blockIdx.x * 256 + threadIdx.x;

    const float4 p = params[b];
    const float beta  = p.x;
    const float gamma = p.y;
    const float S0    = p.z;

    // Rescaled state: u = beta * S  (shortens bSI chain to one mul: bSI = u*I)
    float u = beta * S0;
    float I = p.w;

    const bool  bpos  = (beta > 0.0f);
    const float rbeta = bpos ? (1.0f / beta) : 0.0f;

    const float step = 100.0f / 199.0f;   // linspace step in fp32
    float* o = out + (size_t)b * (NUM_T * 3);
    float tprev = 0.0f;

    for (int g = 0; g < NUM_T / 4; ++g) {
        float buf[12];
        #pragma unroll
        for (int j = 0; j < 4; ++j) {
            const int i = g * 4 + j;
            if (i > 0) {
                // dt exactly as ts[i] - ts[i-1] with ts = i*step (fp32)
                const float tcur = step * (float)i;
                const float dt   = tcur - tprev;
                tprev = tcur;
                const float h  = dt * 0.125f;       // dt / SUBSTEPS
                const float h2 = 0.5f * h;
                const float h6 = h * (1.0f / 6.0f);
                // per-step fused constants (hoisted off the substep chain)
                const float cbA = h2 * beta,  cbB = h * beta,  cbF = h6 * beta;
                const float cgA = h2 * gamma, cgB = h * gamma, cgF = h6 * gamma;
                #pragma unroll
                for (int s = 0; s < 8; ++s) {
                    // stage 1  (kU = -beta*bSI, kI = bSI - gamma*I)
                    const float bSI1 = u * I;
                    const float u2 = fmaf(-cbA, bSI1, u);
                    const float J1 = fmaf(-cgA, I, I);
                    const float I2 = fmaf(h2, bSI1, J1);
                    // stage 2
                    const float bSI2 = u2 * I2;
                    const float u3 = fmaf(-cbA, bSI2, u);
                    const float J2 = fmaf(-cgA, I2, I);
                    const float I3 = fmaf(h2, bSI2, J2);
                    float wb = fmaf(2.0f, bSI2, bSI1);   // bSI1 + 2*bSI2
                    float wI = fmaf(2.0f, I2, I);        // I1 + 2*I2
                    // stage 3
                    const float bSI3 = u3 * I3;
                    const float u4 = fmaf(-cbB, bSI3, u);
                    const float J3 = fmaf(-cgB, I3, I);
                    const float I4 = fmaf(h, bSI3, J3);
                    wb = fmaf(2.0f, bSI3, wb);
                    wI = fmaf(2.0f, I3, wI);
                    // stage 4 (only bSI4, I4 feed the combine)
                    const float bSI4 = u4 * I4;
                    wb += bSI4;
                    wI += I4;
                    // combine:  S += h6*(-wb*beta)/beta ;  I += h6*(wb - gamma*wI)
                    u = fmaf(-cbF, wb, u);
                    const float t = fmaf(-cgF, wI, I);
                    I = fmaf(h6, wb, t);
                }
            }
            const float Sout = bpos ? (u * rbeta) : S0;
            buf[j * 3 + 0] = Sout;
            buf[j * 3 + 1] = I;
            buf[j * 3 + 2] = 1.0f - Sout - I;   // R conserved
        }
        float4* o4 = reinterpret_cast<float4*>(o + g * 12);
        o4[0] = make_float4(buf[0], buf[1], buf[2],  buf[3]);
        o4[1] = make_float4(buf[4], buf[5], buf[6],  buf[7]);
        o4[2] = make_float4(buf[8], buf[9], buf[10], buf[11]);
    }
}

extern "C" void kernel_launch(void* const* d_in, const int* in_sizes, int n_in,
                              void* d_out, int out_size, void* d_ws, size_t ws_size,
                              hipStream_t stream) {
    (void)in_sizes; (void)n_in; (void)out_size; (void)d_ws; (void)ws_size;
    const float4* params = (const float4*)d_in[0];
    float* out = (float*)d_out;
    sir_rk4_kernel<<<NB / 256, 256, 0, stream>>>(params, out);
}